// Round 2
// baseline (954.915 us; speedup 1.0000x reference)
//
#include <hip/hip_runtime.h>

// KW_CascadedBranch round 1:
//   embB = bf16(emb * 10/max(||emb||,eps))   (scale folded -> S-phase needs no scale array)
//   embT = bf16(emb)^T  [512][49408]         (PV B-operand reads are contiguous 16B)
//   attn: QB=32, VS=8 (grid 512 -> 2 blocks/CU), global_load_lds staging, PV-B from embT
//   Opart bf16 (ws budget), combine divides by l.

typedef __attribute__((ext_vector_type(8))) short short8;   // 8 x bf16
typedef __attribute__((ext_vector_type(4))) float f32x4;    // MFMA 16x16x32 acc

#define DM   768
#define TD   512
#define V_   49408
#define M_   2048
#define QB   32
#define NQB  64            // M_/QB
#define VS   8
#define NTT  772           // V_/64 total vocab tiles

__device__ inline unsigned short f2bf(float x){   // RNE f32 -> bf16
  unsigned u = __builtin_bit_cast(unsigned, x);
  u += 0x7fffu + ((u>>16)&1u);
  return (unsigned short)(u>>16);
}
__device__ inline float bf2f(unsigned short u){
  unsigned x = (unsigned)u<<16; return __builtin_bit_cast(float, x);
}
__device__ inline void gload_lds16(const void* g, void* s){
  __builtin_amdgcn_global_load_lds((const __attribute__((address_space(1))) unsigned int*)g,
                                   (__attribute__((address_space(3))) unsigned int*)s, 16, 0, 0);
}

// ---------------- K1: embB = bf16(emb * 10/||emb||) ----------------
__global__ __launch_bounds__(256) void prep_emb(const float* __restrict__ emb,
                                                unsigned short* __restrict__ embB){
  int v = blockIdx.x*4 + (threadIdx.x>>6);   // one wave per vocab row
  int l = threadIdx.x&63;
  const float4* row = (const float4*)(emb + (size_t)v*TD);
  float4 x0 = row[2*l], x1 = row[2*l+1];
  float s = x0.x*x0.x+x0.y*x0.y+x0.z*x0.z+x0.w*x0.w
          + x1.x*x1.x+x1.y*x1.y+x1.z*x1.z+x1.w*x1.w;
  #pragma unroll
  for (int m=1;m<64;m<<=1) s += __shfl_xor(s, m, 64);
  float sc = 10.0f / fmaxf(sqrtf(s), 1e-8f);   // 1/TEMP folded in
  uint4 o;
  o.x = f2bf(x0.x*sc) | ((unsigned)f2bf(x0.y*sc)<<16);
  o.y = f2bf(x0.z*sc) | ((unsigned)f2bf(x0.w*sc)<<16);
  o.z = f2bf(x1.x*sc) | ((unsigned)f2bf(x1.y*sc)<<16);
  o.w = f2bf(x1.z*sc) | ((unsigned)f2bf(x1.w*sc)<<16);
  *((uint4*)(embB + (size_t)v*TD) + l) = o;
}

// ---------------- K1b: embT[d][v] = bf16(emb[v][d]) ----------------
__global__ __launch_bounds__(256) void transp(const float* __restrict__ emb,
                                              unsigned short* __restrict__ embT){
  __shared__ float T[64][68];
  int t = threadIdx.x;
  int v0 = blockIdx.x*64, d0 = blockIdx.y*64;
  int r = t>>4, c4 = t&15;
  #pragma unroll
  for (int p=0;p<4;p++)
    *(float4*)&T[p*16 + r][4*c4] = *(const float4*)(emb + (size_t)(v0+p*16+r)*TD + d0 + 4*c4);
  __syncthreads();
  int wr = t>>3, wc8 = t&7;
  #pragma unroll
  for (int p=0;p<2;p++){
    int d = p*32 + wr;
    unsigned o0 = f2bf(T[8*wc8+0][d]) | ((unsigned)f2bf(T[8*wc8+1][d])<<16);
    unsigned o1 = f2bf(T[8*wc8+2][d]) | ((unsigned)f2bf(T[8*wc8+3][d])<<16);
    unsigned o2 = f2bf(T[8*wc8+4][d]) | ((unsigned)f2bf(T[8*wc8+5][d])<<16);
    unsigned o3 = f2bf(T[8*wc8+6][d]) | ((unsigned)f2bf(T[8*wc8+7][d])<<16);
    *(uint4*)(embT + (size_t)(d0+d)*V_ + v0 + 8*wc8) = make_uint4(o0,o1,o2,o3);
  }
}

// ---------------- K2: kw = audio@W+b, normalize, bf16 ----------------
__global__ __launch_bounds__(512) void proj_kw(const float* __restrict__ audio,
                                               const float* __restrict__ W,
                                               const float* __restrict__ bias,
                                               unsigned short* __restrict__ kwn){
  __shared__ float a[16][772];
  __shared__ float kwt[16][TD];
  int tid = threadIdx.x;
  int row0 = blockIdx.x*16;
  #pragma unroll
  for (int j=0;j<6;j++){
    int idx = tid + 512*j;
    int r = idx/192, c4 = idx%192;
    *(float4*)&a[r][4*c4] = ((const float4*)(audio + (size_t)(row0+r)*DM))[c4];
  }
  __syncthreads();
  int c = tid;
  float acc[16];
  #pragma unroll
  for (int r=0;r<16;r++) acc[r]=0.f;
  float wrA[4], wrB[4];
  #pragma unroll
  for (int kk=0;kk<4;kk++) wrA[kk] = W[(size_t)kk*TD + c];
  for (int k4=0;k4<192;k4+=2){
    #pragma unroll
    for (int kk=0;kk<4;kk++) wrB[kk] = W[(size_t)(4*k4+4+kk)*TD + c];
    #pragma unroll
    for (int r=0;r<16;r++){
      float4 av = *(const float4*)&a[r][4*k4];
      acc[r] += av.x*wrA[0] + av.y*wrA[1] + av.z*wrA[2] + av.w*wrA[3];
    }
    #pragma unroll
    for (int kk=0;kk<4;kk++){ int k = 4*k4+8+kk; if (k>767) k=767; wrA[kk] = W[(size_t)k*TD + c]; }
    #pragma unroll
    for (int r=0;r<16;r++){
      float4 av = *(const float4*)&a[r][4*k4+4];
      acc[r] += av.x*wrB[0] + av.y*wrB[1] + av.z*wrB[2] + av.w*wrB[3];
    }
  }
  float bb = bias[c];
  #pragma unroll
  for (int r=0;r<16;r++) kwt[r][c] = acc[r] + bb;
  __syncthreads();
  int w = tid>>6, l = tid&63;
  #pragma unroll
  for (int rr=0;rr<2;rr++){
    int r = 2*w+rr;
    float4 x0 = *(const float4*)&kwt[r][8*l];
    float4 x1 = *(const float4*)&kwt[r][8*l+4];
    float s = x0.x*x0.x+x0.y*x0.y+x0.z*x0.z+x0.w*x0.w
            + x1.x*x1.x+x1.y*x1.y+x1.z*x1.z+x1.w*x1.w;
    #pragma unroll
    for (int m=1;m<64;m<<=1) s += __shfl_xor(s, m, 64);
    float sc = 1.0f/fmaxf(sqrtf(s), 1e-8f);
    uint4 o;
    o.x = f2bf(x0.x*sc) | ((unsigned)f2bf(x0.y*sc)<<16);
    o.y = f2bf(x0.z*sc) | ((unsigned)f2bf(x0.w*sc)<<16);
    o.z = f2bf(x1.x*sc) | ((unsigned)f2bf(x1.y*sc)<<16);
    o.w = f2bf(x1.z*sc) | ((unsigned)f2bf(x1.w*sc)<<16);
    *((uint4*)(kwn + (size_t)(row0+r)*TD) + l) = o;
  }
}

// ---------------- K3: fused attention over vocab ----------------
// grid = NQB x VS (bid = qb*8+vs -> XCD = vs: per-XCD split locality).
// 8 waves: S-phase wave(qr=w>>2, vp=w&3) computes 16q x 16v; PV wave w owns d-cols [64w,64w+64).
__global__ __launch_bounds__(512,4) void attn(const unsigned short* __restrict__ embB,
                                              const unsigned short* __restrict__ embT,
                                              const unsigned short* __restrict__ kwn,
                                              unsigned short* __restrict__ Opart,
                                              float* __restrict__ lpart){
  __shared__ unsigned short embK[64][520];   // pad 8: row stride 1040B, b128 reads conflict-min
  __shared__ unsigned short P[32][72];       // exp(score) bf16
  __shared__ float l_lds[32];
  int tid = threadIdx.x;
  int w = tid>>6, l = tid&63, c = l&15, g = l>>4;
  int qb = blockIdx.x>>3, vs = blockIdx.x&7;
  int qr = w>>2, vp = w&3;
  int t0 = (NTT*vs)>>3, t1 = (NTT*(vs+1))>>3;   // integer tile splits (96/97 tiles, no tail)
  if (tid<32) l_lds[tid]=0.f;

  // Q fragments in registers: rows qb*32 + qr*16 + c, 16 k-steps (64 VGPR)
  short8 qf[16];
  { const short8* qp = (const short8*)(kwn + (size_t)(qb*QB + qr*16 + c)*TD);
    #pragma unroll
    for (int ks=0;ks<16;ks++) qf[ks] = qp[4*ks+g]; }

  f32x4 acc[2][4];
  #pragma unroll
  for (int i=0;i<2;i++){
    #pragma unroll
    for (int j=0;j<4;j++) acc[i][j] = (f32x4){0.f,0.f,0.f,0.f};
  }
  float l_acc[4] = {0.f,0.f,0.f,0.f};

  // prologue: stage tile t0 (async, drained by loop-top barrier)
  #pragma unroll
  for (int i=0;i<8;i++){
    int vr = 8*i+w;
    gload_lds16(embB + (size_t)(t0*64+vr)*TD + 8*l, &embK[vr][0]);
  }

  for (int t=t0; t<t1; ++t){
    int vb = t*64;
    __syncthreads();                       // drains vmcnt -> embK[t] ready
    // ---- S = Qn . embB^T (scaled logits directly) ----
    f32x4 s0 = (f32x4){0.f,0.f,0.f,0.f};
    { const unsigned short* br = &embK[16*vp + c][0];
      #pragma unroll
      for (int ks=0;ks<16;ks++){
        short8 b0 = *(const short8*)(br + 32*ks + 8*g);
        s0 = __builtin_amdgcn_mfma_f32_16x16x32_bf16(qf[ks], b0, s0, 0,0,0);
      } }
    // ---- exp (|s|<=~10.5, no max-sub), write P, accumulate l in regs ----
    int m0 = 16*qr + 4*g, lv = 16*vp + c;
    #pragma unroll
    for (int j=0;j<4;j++){
      float p = __expf(s0[j]);
      P[m0+j][lv] = f2bf(p);
      l_acc[j] += p;
    }
    __syncthreads();                       // P ready; embK reads done
    if (t+1 < t1){                         // async prefetch next tile under PV
      #pragma unroll
      for (int i=0;i<8;i++){
        int vr = 8*i+w;
        gload_lds16(embB + (size_t)((t+1)*64+vr)*TD + 8*l, &embK[vr][0]);
      }
    }
    // ---- O += P . emb  (B-operand: contiguous 16B loads from embT, L2-resident) ----
    #pragma unroll
    for (int ks=0;ks<2;ks++){
      short8 a0 = *(const short8*)&P[c][32*ks + 8*g];
      short8 a1 = *(const short8*)&P[16 + c][32*ks + 8*g];
      #pragma unroll
      for (int dt=0;dt<4;dt++){
        short8 bv = *(const short8*)(embT + (size_t)(64*w + 16*dt + c)*V_ + vb + 32*ks + 8*g);
        acc[0][dt] = __builtin_amdgcn_mfma_f32_16x16x32_bf16(a0, bv, acc[0][dt], 0,0,0);
        acc[1][dt] = __builtin_amdgcn_mfma_f32_16x16x32_bf16(a1, bv, acc[1][dt], 0,0,0);
      }
    }
  }
  // ---- epilogue: l reduce (over c-lanes, then vp-waves), O write (bf16) ----
  #pragma unroll
  for (int j=0;j<4;j++){
    float s = l_acc[j];
    s += __shfl_xor(s,1,64); s += __shfl_xor(s,2,64);
    s += __shfl_xor(s,4,64); s += __shfl_xor(s,8,64);
    if (c==0) atomicAdd(&l_lds[16*qr + 4*g + j], s);
  }
  __syncthreads();
  unsigned short* op = Opart + (size_t)(qb*VS + vs)*QB*TD;
  #pragma unroll
  for (int qt=0;qt<2;qt++){
    #pragma unroll
    for (int dt=0;dt<4;dt++){
      #pragma unroll
      for (int j=0;j<4;j++)
        op[(size_t)(16*qt + 4*g + j)*TD + 64*w + 16*dt + c] = f2bf(acc[qt][dt][j]);
    }
  }
  if (tid<32) lpart[(size_t)(qb*VS+vs)*QB + tid] = l_lds[tid];
}

// ---------------- K4: combine split-vocab partials ----------------
__global__ __launch_bounds__(256) void combine(const unsigned short* __restrict__ Opart,
                                               const float* __restrict__ lpart,
                                               float* __restrict__ out){
  int m = blockIdx.x;
  int qb = m>>5, r = m&31;
  int t = threadIdx.x;
  float ls = 0.f;
  #pragma unroll
  for (int v=0;v<VS;v++) ls += lpart[(size_t)(qb*VS+v)*QB + r];
  float inv = 1.0f/ls;
  for (int cc=t; cc<TD; cc+=256){
    float s = 0.f;
    #pragma unroll
    for (int v=0;v<VS;v++) s += bf2f(Opart[((size_t)(qb*VS+v)*QB + r)*TD + cc]);
    out[(size_t)m*TD + cc] = s*inv;
  }
}

extern "C" void kernel_launch(void* const* d_in, const int* in_sizes, int n_in,
                              void* d_out, int out_size, void* d_ws, size_t ws_size,
                              hipStream_t stream){
  const float* audio = (const float*)d_in[0];   // [256,8,768]
  const float* W     = (const float*)d_in[1];   // [768,512]
  const float* bias  = (const float*)d_in[2];   // [512]
  const float* emb   = (const float*)d_in[3];   // [49408,512]
  float* out = (float*)d_out;                   // [2048,512] f32
  char* ws = (char*)d_ws;
  // ws layout (total 120,127,488 B)
  unsigned short* embB  = (unsigned short*)(ws);              //  50,593,792
  unsigned short* embT  = (unsigned short*)(ws +  50593792);  //  50,593,792
  unsigned short* kwn   = (unsigned short*)(ws + 101187584);  //   2,097,152
  unsigned short* Opart = (unsigned short*)(ws + 103284736);  //  16,777,216
  float*          lpart = (float*)         (ws + 120061952);  //      65,536

  hipLaunchKernelGGL(prep_emb, dim3(V_/4),      dim3(256), 0, stream, emb, embB);
  hipLaunchKernelGGL(transp,   dim3(V_/64, 8),  dim3(256), 0, stream, emb, embT);
  hipLaunchKernelGGL(proj_kw,  dim3(M_/16),     dim3(512), 0, stream, audio, W, bias, kwn);
  hipLaunchKernelGGL(attn,     dim3(NQB*VS),    dim3(512), 0, stream, embB, embT, kwn, Opart, lpart);
  hipLaunchKernelGGL(combine,  dim3(M_),        dim3(256), 0, stream, Opart, lpart, out);
}

// Round 3
// 765.165 us; speedup vs baseline: 1.2480x; 1.2480x over previous
//
#include <hip/hip_runtime.h>

// KW_CascadedBranch round 2:
//   attn: QB=64, VS=8, grid 256 (1 blk/CU), 8 waves, launch_bounds(512,2) -> 256 VGPR (no spill).
//   Wave S-role: 32q x 16v (two hoisted Q-frag sets) -> each LDS B-read feeds 2 MFMA.
//   embK XOR chunk-swizzle: linear LDS dest, pre-swizzled global src (rule #21), XOR on read.
//   PV B-operand from embT (contiguous 16B, L2); async gload_lds prefetch under PV.
//   Epilogue: O via LDS bounce -> coalesced uint4 stores.

typedef __attribute__((ext_vector_type(8))) short short8;   // 8 x bf16
typedef __attribute__((ext_vector_type(4))) float f32x4;    // MFMA 16x16x32 acc

#define DM   768
#define TD   512
#define V_   49408
#define M_   2048
#define QB   64
#define NQB  32            // M_/QB
#define VS   8
#define NTT  772           // V_/64 (exact: 772*64 = 49408, no partial tiles)

__device__ inline unsigned short f2bf(float x){   // RNE f32 -> bf16
  unsigned u = __builtin_bit_cast(unsigned, x);
  u += 0x7fffu + ((u>>16)&1u);
  return (unsigned short)(u>>16);
}
__device__ inline float bf2f(unsigned short u){
  unsigned x = (unsigned)u<<16; return __builtin_bit_cast(float, x);
}
__device__ inline void gload_lds16(const void* g, void* s){
  __builtin_amdgcn_global_load_lds((const __attribute__((address_space(1))) unsigned int*)g,
                                   (__attribute__((address_space(3))) unsigned int*)s, 16, 0, 0);
}

// ---------------- K1: embB = bf16(emb * 10/||emb||) ----------------
__global__ __launch_bounds__(256) void prep_emb(const float* __restrict__ emb,
                                                unsigned short* __restrict__ embB){
  int v = blockIdx.x*4 + (threadIdx.x>>6);
  int l = threadIdx.x&63;
  const float4* row = (const float4*)(emb + (size_t)v*TD);
  float4 x0 = row[2*l], x1 = row[2*l+1];
  float s = x0.x*x0.x+x0.y*x0.y+x0.z*x0.z+x0.w*x0.w
          + x1.x*x1.x+x1.y*x1.y+x1.z*x1.z+x1.w*x1.w;
  #pragma unroll
  for (int m=1;m<64;m<<=1) s += __shfl_xor(s, m, 64);
  float sc = 10.0f / fmaxf(sqrtf(s), 1e-8f);   // 1/TEMP folded in
  uint4 o;
  o.x = f2bf(x0.x*sc) | ((unsigned)f2bf(x0.y*sc)<<16);
  o.y = f2bf(x0.z*sc) | ((unsigned)f2bf(x0.w*sc)<<16);
  o.z = f2bf(x1.x*sc) | ((unsigned)f2bf(x1.y*sc)<<16);
  o.w = f2bf(x1.z*sc) | ((unsigned)f2bf(x1.w*sc)<<16);
  *((uint4*)(embB + (size_t)v*TD) + l) = o;
}

// ---------------- K1b: embT[d][v] = bf16(emb[v][d]) ----------------
__global__ __launch_bounds__(256) void transp(const float* __restrict__ emb,
                                              unsigned short* __restrict__ embT){
  __shared__ float T[64][68];
  int t = threadIdx.x;
  int v0 = blockIdx.x*64, d0 = blockIdx.y*64;
  int r = t>>4, c4 = t&15;
  #pragma unroll
  for (int p=0;p<4;p++)
    *(float4*)&T[p*16 + r][4*c4] = *(const float4*)(emb + (size_t)(v0+p*16+r)*TD + d0 + 4*c4);
  __syncthreads();
  int wr = t>>3, wc8 = t&7;
  #pragma unroll
  for (int p=0;p<2;p++){
    int d = p*32 + wr;
    unsigned o0 = f2bf(T[8*wc8+0][d]) | ((unsigned)f2bf(T[8*wc8+1][d])<<16);
    unsigned o1 = f2bf(T[8*wc8+2][d]) | ((unsigned)f2bf(T[8*wc8+3][d])<<16);
    unsigned o2 = f2bf(T[8*wc8+4][d]) | ((unsigned)f2bf(T[8*wc8+5][d])<<16);
    unsigned o3 = f2bf(T[8*wc8+6][d]) | ((unsigned)f2bf(T[8*wc8+7][d])<<16);
    *(uint4*)(embT + (size_t)(d0+d)*V_ + v0 + 8*wc8) = make_uint4(o0,o1,o2,o3);
  }
}

// ---------------- K2: kw = audio@W+b, normalize, bf16 ----------------
__global__ __launch_bounds__(512) void proj_kw(const float* __restrict__ audio,
                                               const float* __restrict__ W,
                                               const float* __restrict__ bias,
                                               unsigned short* __restrict__ kwn){
  __shared__ float a[16][772];
  __shared__ float kwt[16][TD];
  int tid = threadIdx.x;
  int row0 = blockIdx.x*16;
  #pragma unroll
  for (int j=0;j<6;j++){
    int idx = tid + 512*j;
    int r = idx/192, c4 = idx%192;
    *(float4*)&a[r][4*c4] = ((const float4*)(audio + (size_t)(row0+r)*DM))[c4];
  }
  __syncthreads();
  int c = tid;
  float acc[16];
  #pragma unroll
  for (int r=0;r<16;r++) acc[r]=0.f;
  float wrA[4], wrB[4];
  #pragma unroll
  for (int kk=0;kk<4;kk++) wrA[kk] = W[(size_t)kk*TD + c];
  for (int k4=0;k4<192;k4+=2){
    #pragma unroll
    for (int kk=0;kk<4;kk++) wrB[kk] = W[(size_t)(4*k4+4+kk)*TD + c];
    #pragma unroll
    for (int r=0;r<16;r++){
      float4 av = *(const float4*)&a[r][4*k4];
      acc[r] += av.x*wrA[0] + av.y*wrA[1] + av.z*wrA[2] + av.w*wrA[3];
    }
    #pragma unroll
    for (int kk=0;kk<4;kk++){ int k = 4*k4+8+kk; if (k>767) k=767; wrA[kk] = W[(size_t)k*TD + c]; }
    #pragma unroll
    for (int r=0;r<16;r++){
      float4 av = *(const float4*)&a[r][4*k4+4];
      acc[r] += av.x*wrB[0] + av.y*wrB[1] + av.z*wrB[2] + av.w*wrB[3];
    }
  }
  float bb = bias[c];
  #pragma unroll
  for (int r=0;r<16;r++) kwt[r][c] = acc[r] + bb;
  __syncthreads();
  int w = tid>>6, l = tid&63;
  #pragma unroll
  for (int rr=0;rr<2;rr++){
    int r = 2*w+rr;
    float4 x0 = *(const float4*)&kwt[r][8*l];
    float4 x1 = *(const float4*)&kwt[r][8*l+4];
    float s = x0.x*x0.x+x0.y*x0.y+x0.z*x0.z+x0.w*x0.w
            + x1.x*x1.x+x1.y*x1.y+x1.z*x1.z+x1.w*x1.w;
    #pragma unroll
    for (int m=1;m<64;m<<=1) s += __shfl_xor(s, m, 64);
    float sc = 1.0f/fmaxf(sqrtf(s), 1e-8f);
    uint4 o;
    o.x = f2bf(x0.x*sc) | ((unsigned)f2bf(x0.y*sc)<<16);
    o.y = f2bf(x0.z*sc) | ((unsigned)f2bf(x0.w*sc)<<16);
    o.z = f2bf(x1.x*sc) | ((unsigned)f2bf(x1.y*sc)<<16);
    o.w = f2bf(x1.z*sc) | ((unsigned)f2bf(x1.w*sc)<<16);
    *((uint4*)(kwn + (size_t)(row0+r)*TD) + l) = o;
  }
}

// ---------------- K3: fused attention over vocab ----------------
// grid = NQB x VS (bid&7 = vs -> XCD-pinned vocab split). 8 waves, 1 blk/CU.
// S-phase: wave (qr=w>>2, vp=w&3) computes 32q x 16v (2 hoisted Q-frag sets).
// PV: wave w owns d-cols [64w, 64w+64), B from embT.
__global__ __launch_bounds__(512,2) void attn(const unsigned short* __restrict__ embB,
                                              const unsigned short* __restrict__ embT,
                                              const unsigned short* __restrict__ kwn,
                                              unsigned short* __restrict__ Opart,
                                              float* __restrict__ lpart){
  __shared__ unsigned short embK[64*512];   // linear rows; chunk-XOR-swizzled content
  __shared__ unsigned short P[64][72];      // exp(score) bf16, [q][v]
  __shared__ float l_lds[64];
  int tid = threadIdx.x;
  int w = tid>>6, l = tid&63, c = l&15, g = l>>4;
  int qb = blockIdx.x>>3, vs = blockIdx.x&7;
  int qr = w>>2, vp = w&3;
  int t0 = (NTT*vs)>>3, t1 = (NTT*(vs+1))>>3;   // 96/97-tile splits, all tiles full
  if (tid<64) l_lds[tid]=0.f;

  // hoist Q: rows qb*64 + 32*qr + {c, 16+c}, 16 k-steps each (128 VGPR)
  short8 qfA[16], qfB[16];
  { const short8* qpA = (const short8*)(kwn + (size_t)(qb*QB + 32*qr + c)*TD);
    const short8* qpB = (const short8*)(kwn + (size_t)(qb*QB + 32*qr + 16 + c)*TD);
    #pragma unroll
    for (int ks=0;ks<16;ks++){ qfA[ks] = qpA[4*ks+g]; qfB[ks] = qpB[4*ks+g]; } }

  f32x4 acc[4][4];
  #pragma unroll
  for (int i=0;i<4;i++){
    #pragma unroll
    for (int j=0;j<4;j++) acc[i][j] = (f32x4){0.f,0.f,0.f,0.f};
  }
  float l_acc[2][4] = {{0.f,0.f,0.f,0.f},{0.f,0.f,0.f,0.f}};

  // stage tile t: wave w stages rows 8i+w; LDS linear (base+16*lane),
  // global source chunk pre-swizzled: lane l <- chunk l ^ (row&7)   [rule #21]
#define STAGE(tt)                                                              \
  { _Pragma("unroll")                                                          \
    for (int i=0;i<8;i++){                                                     \
      int vr = 8*i+w;                                                          \
      gload_lds16(embB + (size_t)((tt)*64+vr)*TD + 8*(l ^ (vr&7)),             \
                  &embK[vr*TD]);                                               \
    } }

  STAGE(t0);

  for (int t=t0; t<t1; ++t){
    __syncthreads();                       // drains vmcnt -> embK[t] ready
    // ---- S = Qn . embB^T : 16 B-reads feed 32 MFMA ----
    f32x4 s0 = (f32x4){0.f,0.f,0.f,0.f};
    f32x4 s1 = (f32x4){0.f,0.f,0.f,0.f};
    { const unsigned short* br = &embK[(16*vp + c)*TD];
      int sw = (c&7)<<3;                   // element-offset XOR key (chunk^(row&7))*8
      #pragma unroll
      for (int ks=0;ks<16;ks++){
        short8 b = *(const short8*)(br + ((32*ks + 8*g) ^ sw));
        s0 = __builtin_amdgcn_mfma_f32_16x16x32_bf16(qfA[ks], b, s0, 0,0,0);
        s1 = __builtin_amdgcn_mfma_f32_16x16x32_bf16(qfB[ks], b, s1, 0,0,0);
      } }
    // ---- exp (|s|<=~10.5, no max-sub), write P, accumulate l in regs ----
    int lv = 16*vp + c;
    #pragma unroll
    for (int j=0;j<4;j++){
      float p0 = __expf(s0[j]);
      float p1 = __expf(s1[j]);
      P[32*qr + 4*g + j][lv]      = f2bf(p0);
      P[32*qr + 16 + 4*g + j][lv] = f2bf(p1);
      l_acc[0][j] += p0;
      l_acc[1][j] += p1;
    }
    __syncthreads();                       // P ready; embK fully consumed
    if (t+1 < t1) STAGE(t+1);              // async prefetch under PV
    // ---- O += P . emb (B: contiguous 16B from embT, L2-resident) ----
    int vb = t*64;
    #pragma unroll
    for (int ks=0;ks<2;ks++){
      short8 af[4];
      #pragma unroll
      for (int qt=0;qt<4;qt++) af[qt] = *(const short8*)&P[16*qt + c][32*ks + 8*g];
      #pragma unroll
      for (int dt=0;dt<4;dt++){
        short8 bv = *(const short8*)(embT + (size_t)(64*w + 16*dt + c)*V_ + vb + 32*ks + 8*g);
        #pragma unroll
        for (int qt=0;qt<4;qt++)
          acc[qt][dt] = __builtin_amdgcn_mfma_f32_16x16x32_bf16(af[qt], bv, acc[qt][dt], 0,0,0);
      }
    }
  }
#undef STAGE

  // ---- epilogue: l reduce (c-lanes, then vp-waves via LDS atomics) ----
  #pragma unroll
  for (int h=0;h<2;h++){
    #pragma unroll
    for (int j=0;j<4;j++){
      float s = l_acc[h][j];
      s += __shfl_xor(s,1,64); s += __shfl_xor(s,2,64);
      s += __shfl_xor(s,4,64); s += __shfl_xor(s,8,64);
      if (c==0) atomicAdd(&l_lds[32*qr + 16*h + 4*g + j], s);
    }
  }
  __syncthreads();                         // l done; all waves past last PV
  // O bounce: scatter bf16 into embK as O[64][512], then coalesced copy out
  #pragma unroll
  for (int qt=0;qt<4;qt++){
    #pragma unroll
    for (int dt=0;dt<4;dt++){
      #pragma unroll
      for (int j=0;j<4;j++)
        embK[(16*qt + 4*g + j)*TD + 64*w + 16*dt + c] = f2bf(acc[qt][dt][j]);
    }
  }
  if (tid<64) lpart[(size_t)(qb*VS+vs)*QB + tid] = l_lds[tid];
  __syncthreads();
  { unsigned short* op = Opart + (size_t)(qb*VS + vs)*QB*TD;
    const uint4* s4 = (const uint4*)embK;
    uint4* d4 = (uint4*)op;
    #pragma unroll
    for (int i=0;i<8;i++) d4[tid + 512*i] = s4[tid + 512*i];   // 64KB coalesced
  }
}

// ---------------- K4: combine split-vocab partials ----------------
__global__ __launch_bounds__(256) void combine(const unsigned short* __restrict__ Opart,
                                               const float* __restrict__ lpart,
                                               float* __restrict__ out){
  int m = blockIdx.x;
  int qb = m>>6, r = m&63;
  int t = threadIdx.x;
  float ls = 0.f;
  #pragma unroll
  for (int v=0;v<VS;v++) ls += lpart[(size_t)(qb*VS+v)*QB + r];
  float inv = 1.0f/ls;
  for (int cc=t; cc<TD; cc+=256){
    float s = 0.f;
    #pragma unroll
    for (int v=0;v<VS;v++) s += bf2f(Opart[((size_t)(qb*VS+v)*QB + r)*TD + cc]);
    out[(size_t)m*TD + cc] = s*inv;
  }
}

extern "C" void kernel_launch(void* const* d_in, const int* in_sizes, int n_in,
                              void* d_out, int out_size, void* d_ws, size_t ws_size,
                              hipStream_t stream){
  const float* audio = (const float*)d_in[0];   // [256,8,768]
  const float* W     = (const float*)d_in[1];   // [768,512]
  const float* bias  = (const float*)d_in[2];   // [512]
  const float* emb   = (const float*)d_in[3];   // [49408,512]
  float* out = (float*)d_out;                   // [2048,512] f32
  char* ws = (char*)d_ws;
  // ws layout (total 120,127,488 B)
  unsigned short* embB  = (unsigned short*)(ws);              //  50,593,792
  unsigned short* embT  = (unsigned short*)(ws +  50593792);  //  50,593,792
  unsigned short* kwn   = (unsigned short*)(ws + 101187584);  //   2,097,152
  unsigned short* Opart = (unsigned short*)(ws + 103284736);  //  16,777,216
  float*          lpart = (float*)         (ws + 120061952);  //      65,536

  hipLaunchKernelGGL(prep_emb, dim3(V_/4),      dim3(256), 0, stream, emb, embB);
  hipLaunchKernelGGL(transp,   dim3(V_/64, 8),  dim3(256), 0, stream, emb, embT);
  hipLaunchKernelGGL(proj_kw,  dim3(M_/16),     dim3(512), 0, stream, audio, W, bias, kwn);
  hipLaunchKernelGGL(attn,     dim3(NQB*VS),    dim3(512), 0, stream, embB, embT, kwn, Opart, lpart);
  hipLaunchKernelGGL(combine,  dim3(M_),        dim3(256), 0, stream, Opart, lpart, out);
}